// Round 7
// baseline (651.827 us; speedup 1.0000x reference)
//
#include <hip/hip_runtime.h>
#include <cstdint>
#include <cstddef>

// ---------------------------------------------------------------------------
// AFMADE block: 16-step autoregressive inversion of two 3-layer MADE MLPs.
// D=16, H=1024, B=2048.
// R7 structure: h0 is never materialized. Each GEMM block regenerates its
// A-subtile per K-tile via a K=16 mini-MFMA from y (elu(y@W0'+b0)), where y
// is recomputed in the prologue from the previous step's layer-2 partials.
// Degree-sorted space (W1' block-lower-triangular, ktN = min(nt+2,16)).
// LDS: sA stride-72 (conflict-free), W1/W0p staged via XOR-swizzled
// global_load_lds, double-buffered, 2 barriers/K-tile. 18 dispatches total.
// ---------------------------------------------------------------------------

#define Dd 16
#define Hh 1024
#define Bb 2048
#define EPSV 1e-12f

typedef unsigned short u16;
typedef __attribute__((ext_vector_type(4))) float f32x4;
typedef __attribute__((ext_vector_type(8))) short s16x8;
typedef __attribute__((ext_vector_type(4))) u16 u16x4;
typedef __attribute__((ext_vector_type(8))) u16 u16x8;

__device__ __forceinline__ u16 f2bf(float f) {
  union { float f; unsigned u; } v; v.f = f;
  unsigned u = v.u;
  unsigned r = (u + 0x7fffu + ((u >> 16) & 1u)) >> 16;  // RNE
  return (u16)r;
}
__device__ __forceinline__ float bf2f(u16 u) {
  union { unsigned u; float f; } v; v.u = ((unsigned)u) << 16;
  return v.f;
}
__device__ __forceinline__ float elu(float a) {
  return a > 0.f ? a : __expf(a) - 1.f;
}
__device__ __forceinline__ void gl_lds16(const void* g, void* l) {
  __builtin_amdgcn_global_load_lds(
      (const __attribute__((address_space(1))) void*)g,
      (__attribute__((address_space(3))) void*)l, 16, 0, 0);
}

// Degree-sort permutation: group g = j%15; groups 0..3 have 69, 4..14 have 68.
__device__ __forceinline__ int p_of(int i) {
  if (i < 276) { int g = i / 69, q = i - g * 69; return g + 15 * q; }
  int r = i - 276; int g = 4 + r / 68, q = r - (g - 4) * 68;
  return g + 15 * q;
}
__device__ __forceinline__ int g_of(int i) {
  return (i < 276) ? (i / 69) : (4 + (i - 276) / 68);
}

// --------------------------- prep (one dispatch) ---------------------------
// All 512 blocks: one W1' row per wave (2048 rows). Blocks 0..7: W0p + b0s.
// Blocks 8..15: W2'.
__global__ __launch_bounds__(256) void prep_all(
    const float* __restrict__ mu_v0, const float* __restrict__ mu_g0,
    const float* __restrict__ mu_b0,
    const float* __restrict__ mu_v1, const float* __restrict__ mu_g1,
    const float* __restrict__ mu_b1,
    const float* __restrict__ mu_v2, const float* __restrict__ mu_g2,
    const float* __restrict__ lv_v0, const float* __restrict__ lv_g0,
    const float* __restrict__ lv_b0,
    const float* __restrict__ lv_v1, const float* __restrict__ lv_g1,
    const float* __restrict__ lv_b1,
    const float* __restrict__ lv_v2, const float* __restrict__ lv_g2,
    u16* __restrict__ W1, float* __restrict__ b1s,
    u16* __restrict__ W0p, float* __restrict__ b0s,
    u16* __restrict__ W2) {
  int bid = blockIdx.x, tid = threadIdx.x;
  int l = tid & 63, w = tid >> 6;
  {  // W1' row
    int wid = bid * 4 + w;
    int net = wid >> 10, i = wid & 1023;
    int j = p_of(i), gi = g_of(i);
    const float* v = (net ? lv_v1 : mu_v1) + (size_t)j * Hh;
    float val[4][4]; float ss = 0.f;
    for (int ii = 0; ii < 4; ++ii)
      for (int t = 0; t < 4; ++t) {
        int kp = ii * 256 + 4 * l + t;
        float xx = v[p_of(kp)];
        val[ii][t] = xx; ss += xx * xx;
      }
    for (int s = 32; s; s >>= 1) ss += __shfl_xor(ss, s);
    float sc = ((net ? lv_g1 : mu_g1)[j]) * rsqrtf(ss);
    u16* o = W1 + (size_t)wid * Hh;
    for (int ii = 0; ii < 4; ++ii) {
      int k0 = ii * 256 + 4 * l;
      u16x4 wv;
      for (int t = 0; t < 4; ++t)
        wv[t] = f2bf((gi >= g_of(k0 + t)) ? sc * val[ii][t] : 0.f);
      *(u16x4*)(o + k0) = wv;
    }
    if (l == 0) b1s[wid] = (net ? lv_b1 : mu_b1)[j];
  }
  if (bid < 8) {  // W0p: padded [2048][32], cols 16..31 zero; b0s sorted
    int idx = bid * 256 + tid;
    int net = idx >> 10, i = idx & 1023;
    int j = p_of(i), gi = g_of(i);
    const float* v = (net ? lv_v0 : mu_v0) + j * Dd;
    float vv[16]; float ss = 0.f;
    for (int k = 0; k < 16; ++k) { vv[k] = v[k]; ss += vv[k] * vv[k]; }
    float sc = ((net ? lv_g0 : mu_g0)[j]) * rsqrtf(ss);
    u16* o = W0p + (size_t)idx * 32;
    for (int k = 0; k < 16; ++k) o[k] = f2bf((gi >= k) ? sc * vv[k] : 0.f);
    for (int k = 16; k < 32; ++k) o[k] = 0;
    b0s[idx] = (net ? lv_b0 : mu_b0)[j];
  }
  if (bid >= 8 && bid < 16) {  // W2' rows (32)
    int wid = (bid - 8) * 4 + w;
    int net = wid >> 4, oi = wid & 15;
    const float* v = (net ? lv_v2 : mu_v2) + (size_t)oi * Hh;
    float val[4][4]; float ss = 0.f;
    for (int ii = 0; ii < 4; ++ii)
      for (int t = 0; t < 4; ++t) {
        int kp = ii * 256 + 4 * l + t;
        float xx = v[p_of(kp)];
        val[ii][t] = xx; ss += xx * xx;
      }
    for (int s = 32; s; s >>= 1) ss += __shfl_xor(ss, s);
    float sc = ((net ? lv_g2 : mu_g2)[oi]) * rsqrtf(ss);
    u16* o = W2 + (size_t)wid * Hh;
    for (int ii = 0; ii < 4; ++ii) {
      int k0 = ii * 256 + 4 * l;
      u16x4 wv;
      for (int t = 0; t < 4; ++t)
        wv[t] = f2bf((oi > g_of(k0 + t)) ? sc * val[ii][t] : 0.f);
      *(u16x4*)(o + k0) = wv;
    }
  }
}

// --------------------------- fused step GEMM -------------------------------
// Grid 512 = 2 halves x {2 net x 16 mt x 8 jj}; half0 nt=jj, half1 nt=15-jj.
// Per block: prologue reduces partSrc -> mu/lv -> y (bf16, LDS), then the
// K-loop generates A-subtiles from y@W0p (8 MFMA), stages W1 (dbuf, XOR-
// swizzled), main MFMA; epilogue elu+layer2 mini-GEMM -> partDst.
__global__ __launch_bounds__(256, 2) void gemm_fused(
    const float* __restrict__ partSrc, float* __restrict__ partDst,
    const u16* __restrict__ W1, const float* __restrict__ b1s,
    const u16* __restrict__ W2, const u16* __restrict__ W0p,
    const float* __restrict__ b0s,
    const float* __restrict__ b2_mu, const float* __restrict__ b2_lv,
    const float* __restrict__ x, int first) {
  // LDS regions (bytes):
  //  sA   @0      : 128x72 u16 = 18432 (gen-A out / epilogue sH)
  //  sBd  @18432  : 2 x 64x64 u16 = 16384 (W1 dbuf, XOR-swizzled)
  //  sWd  @34816  : 2 x 64x32 u16 = 8192  (W0p dbuf, XOR-swizzled)
  //  yb   @43008  : 128x40 u16 = 10240 (cols 0..31 used, 16..31 zero)
  //  sB0  @53248  : 1024 f32 = 4096
  //  sW2b @57344  : 16x72 u16 = 2304
  // overlays (prologue only): sStage f32[2][16][256]=32768 @0; sML
  // f32[128][32]=16384 @34816 (dead before sWd/yb go live).
  __shared__ __align__(16) char sm[59648];
  u16*   sA   = (u16*)(sm);
  u16*   sBd  = (u16*)(sm + 18432);
  u16*   sWd  = (u16*)(sm + 34816);
  u16*   yb   = (u16*)(sm + 43008);
  float* sB0  = (float*)(sm + 53248);
  u16*   sW2b = (u16*)(sm + 57344);
  float* sStage = (float*)sm;
  float* sML    = (float*)(sm + 34816);

  const int bid = blockIdx.x, tid = threadIdx.x;
  const int l = tid & 63, w = tid >> 6;
  const int q = bid & 255, half = bid >> 8;
  const int net = q >> 7, r = q & 127;
  const int mt = r >> 3, jj = r & 7;
  const int nt = half ? (15 - jj) : jj;
  const int ktN = nt + 2 < 16 ? nt + 2 : 16;
  const int m0 = mt * 128, n0 = nt * 64;
  const u16* W1n  = W1 + (size_t)net * (Hh * Hh);
  const u16* W0pn = W0p + (size_t)net * (1024 * 32);
  const int wr = w >> 1, wc = w & 1;
  const int lr = l & 15, lk = l >> 4;

  // W2 column tile -> sW2b (stride 72)
  for (int c = 0; c < 4; ++c) {
    int e = c * 256 + tid;
    int i = e >> 6, col = e & 63;
    sW2b[i * 72 + col] = W2[(size_t)(net * 16 + i) * Hh + n0 + col];
  }

  // ---- prologue: part -> mu/lv -> y ----
  float muS[8], lvS[8];
  if (!first) {
    for (int p = 0; p < 8; ++p) {
      __syncthreads();  // sStage free (prev pass readers / sW2b writes done)
      for (int c = 0; c < 8; ++c) {
        int i4 = c * 256 + tid;          // f32x4 chunk id, 0..2047
        int e = i4 * 4;
        int nn = e >> 12, r16 = (e >> 8) & 15, col = e & 255;
        gl_lds16(partSrc + ((size_t)(nn * Bb) + m0 + p * 16 + r16) * 256 + col,
                 (char*)sStage + i4 * 16);
      }
      __syncthreads();  // vmcnt drained + visible
      for (int o2 = 0; o2 < 2; ++o2) {
        int o = o2 * 256 + tid;          // 0..511
        int nn = o >> 8, r16 = (o >> 4) & 15, i = o & 15;
        float ssum = 0.f;
        for (int ntc = 0; ntc < 16; ++ntc)
          ssum += sStage[nn * 4096 + r16 * 256 + ntc * 16 + i];
        sML[(p * 16 + r16) * 32 + nn * 16 + i] =
            ssum + (nn ? b2_lv : b2_mu)[i];
      }
    }
    __syncthreads();
    // snapshot this thread's 8 (mu,lv) pairs
    for (int qq = 0; qq < 8; ++qq) {
      int rd = tid * 8 + qq;
      int row = rd >> 4, d = rd & 15;
      muS[qq] = sML[row * 32 + d];
      lvS[qq] = sML[row * 32 + 16 + d];
    }
  }
  __syncthreads();  // sML snapshot done; sStage dead -> stage kt0 + sB0

  // stage kt=0 (W1 + W0p swizzled) and sB0
  {
    for (int c = 0; c < 2; ++c) {
      int qq = c * 256 + tid, row = qq >> 3, cc = qq & 7;
      gl_lds16(W1n + (size_t)(n0 + row) * Hh + ((cc ^ (row & 7)) * 8),
               (char*)sBd + qq * 16);
    }
    {
      int qq = tid, row = qq >> 2, cc = qq & 3;
      gl_lds16(W0pn + (size_t)row * 32 + ((cc ^ (row & 3)) * 8),
               (char*)sWd + qq * 16);
    }
    gl_lds16(b0s + net * 1024 + tid * 4, (char*)sB0 + tid * 16);
  }

  // y -> yb (bf16, stride 40, cols 16..31 zero)
  if (first) {
    for (int qq = 0; qq < 8; ++qq) {
      int rd = tid * 8 + qq;
      int row = rd >> 4, d = rd & 15;
      yb[row * 40 + d] = 0;
      yb[row * 40 + 16 + d] = 0;
    }
  } else {
    int row0 = tid >> 1, d0 = (tid & 1) * 8;
    f32x4 xa = *(const f32x4*)(x + (m0 + row0) * 16 + d0);
    f32x4 xb2 = *(const f32x4*)(x + (m0 + row0) * 16 + d0 + 4);
    for (int qq = 0; qq < 8; ++qq) {
      int rd = tid * 8 + qq;
      int row = rd >> 4, d = rd & 15;
      float xv = (qq < 4) ? xa[qq] : xb2[qq - 4];
      float yv = (xv - muS[qq]) / (__expf(0.5f * lvS[qq]) + EPSV);
      yb[row * 40 + d] = f2bf(yv);
      yb[row * 40 + 16 + d] = 0;
    }
  }
  __syncthreads();  // kt0 staged (vmcnt0), yb visible

  // ---- K loop ----
  f32x4 acc[4][2] = {};
  for (int kt = 0; kt < ktN; ++kt) {
    const int idx = kt & 1;
    if (kt + 1 < ktN) {  // prefetch kt+1 into other buffers
      int kb = (kt + 1) * 64;
      for (int c = 0; c < 2; ++c) {
        int qq = c * 256 + tid, row = qq >> 3, cc = qq & 7;
        gl_lds16(W1n + (size_t)(n0 + row) * Hh + kb + ((cc ^ (row & 7)) * 8),
                 (char*)sBd + (idx ^ 1) * 8192 + qq * 16);
      }
      int qq = tid, row = qq >> 2, cc = qq & 3;
      gl_lds16(W0pn + (size_t)(kb + row) * 32 + ((cc ^ (row & 3)) * 8),
               (char*)sWd + (idx ^ 1) * 4096 + qq * 16);
    }
    // gen-A: A-subtile[128][64] = elu(y @ W0p_kt + b0), wave w rows w*32..+31
    {
      const u16* sW = sWd + idx * 2048;  // u16 elems
      for (int mi2 = 0; mi2 < 2; ++mi2) {
        int arow = w * 32 + mi2 * 16 + lr;
        s16x8 afG = *(const s16x8*)(yb + arow * 40 + lk * 8);
        for (int c4 = 0; c4 < 4; ++c4) {
          int brow = c4 * 16 + lr;
          s16x8 bfG = *(const s16x8*)(sW + brow * 32 + ((lk ^ (brow & 3)) * 8));
          f32x4 aG = __builtin_amdgcn_mfma_f32_16x16x32_bf16(
              afG, bfG, (f32x4){0.f, 0.f, 0.f, 0.f}, 0, 0, 0);
          int col = c4 * 16 + lr;
          float bias = sB0[kt * 64 + col];
          for (int rr2 = 0; rr2 < 4; ++rr2) {
            int orow = w * 32 + mi2 * 16 + lk * 4 + rr2;
            sA[orow * 72 + col] = f2bf(elu(aG[rr2] + bias));
          }
        }
      }
    }
    __syncthreads();  // sA visible + kt+1 prefetch drained (vmcnt0)
    // main MFMA
    {
      const u16* sB = sBd + idx * 4096;  // u16 elems
      for (int kk = 0; kk < 2; ++kk) {
        int ko = kk * 32 + lk * 8;
        int cidx = kk * 4 + lk;
        s16x8 af[4], bfr[2];
        for (int mi = 0; mi < 4; ++mi)
          af[mi] = *(const s16x8*)(sA + (wr * 64 + mi * 16 + lr) * 72 + ko);
        for (int ni = 0; ni < 2; ++ni) {
          int brow = wc * 32 + ni * 16 + lr;
          bfr[ni] = *(const s16x8*)(sBd + idx * 4096 + brow * 64 +
                                    ((cidx ^ (brow & 7)) * 8));
        }
        for (int mi = 0; mi < 4; ++mi)
          for (int ni = 0; ni < 2; ++ni)
            acc[mi][ni] = __builtin_amdgcn_mfma_f32_16x16x32_bf16(
                af[mi], bfr[ni], acc[mi][ni], 0, 0, 0);
      }
      (void)sB;
    }
    __syncthreads();  // all reads done before next gen-A / prefetch overwrite
  }

  // ---- epilogue: h1 -> sA (stride 72), mini-GEMM vs W2 -> partDst ----
  for (int ni = 0; ni < 2; ++ni) {
    int col = wc * 32 + ni * 16 + lr;
    float bias = b1s[net * 1024 + n0 + col];
    for (int mi = 0; mi < 4; ++mi)
      for (int rr2 = 0; rr2 < 4; ++rr2) {
        int row = wr * 64 + mi * 16 + lk * 4 + rr2;
        sA[row * 72 + col] = f2bf(elu(acc[mi][ni][rr2] + bias));
      }
  }
  __syncthreads();
  {
    f32x4 acc2[2] = {};
    for (int kk = 0; kk < 2; ++kk) {
      int ko = kk * 32 + lk * 8;
      s16x8 bfr = *(const s16x8*)(sW2b + lr * 72 + ko);
      for (int mi = 0; mi < 2; ++mi) {
        s16x8 af = *(const s16x8*)(sA + (w * 32 + mi * 16 + lr) * 72 + ko);
        acc2[mi] = __builtin_amdgcn_mfma_f32_16x16x32_bf16(
            af, bfr, acc2[mi], 0, 0, 0);
      }
    }
    for (int mi = 0; mi < 2; ++mi)
      for (int rr2 = 0; rr2 < 4; ++rr2) {
        int row = m0 + w * 32 + mi * 16 + lk * 4 + rr2;
        partDst[((size_t)(net * Bb) + row) * 256 + nt * 16 + lr] = acc2[mi][rr2];
      }
  }
}

// --------------------------- final outputs ---------------------------------
// 128 blocks x 256 threads; 16 rows/block: reduce part -> mu/lv -> y, out.
__global__ __launch_bounds__(256) void step_final(
    const float* __restrict__ partSrc,
    const float* __restrict__ b2_mu, const float* __restrict__ b2_lv,
    const float* __restrict__ x, float* __restrict__ out) {
  __shared__ float sStage[2][16][256];
  __shared__ float sML[16][32];
  int tid = threadIdx.x;
  int b0g = blockIdx.x * 16;
  for (int c = 0; c < 8; ++c) {
    int i4 = c * 256 + tid;
    int e = i4 * 4;
    int nn = e >> 12, r16 = (e >> 8) & 15, col = e & 255;
    *(f32x4*)&sStage[nn][r16][col] =
        *(const f32x4*)(partSrc + ((size_t)(nn * Bb) + b0g + r16) * 256 + col);
  }
  __syncthreads();
  for (int o2 = 0; o2 < 2; ++o2) {
    int o = o2 * 256 + tid;
    int nn = o >> 8, r16 = (o >> 4) & 15, i = o & 15;
    float ssum = 0.f;
    for (int ntc = 0; ntc < 16; ++ntc) ssum += sStage[nn][r16][ntc * 16 + i];
    sML[r16][nn * 16 + i] = ssum + (nn ? b2_lv : b2_mu)[i];
  }
  __syncthreads();
  {
    int r16 = tid >> 4, d = tid & 15;
    int b = b0g + r16;
    float mu = sML[r16][d];
    float ls = 0.5f * sML[r16][16 + d];
    float yn = (x[b * 16 + d] - mu) / (__expf(ls) + EPSV);
    out[b * 16 + d] = yn;
    float pp = ls;
    pp += __shfl_xor(pp, 1);
    pp += __shfl_xor(pp, 2);
    pp += __shfl_xor(pp, 4);
    pp += __shfl_xor(pp, 8);
    if (d == 0) out[Bb * 16 + b] = pp;
  }
}

// --------------------------- launch ----------------------------------------

extern "C" void kernel_launch(void* const* d_in, const int* in_sizes, int n_in,
                              void* d_out, int out_size, void* d_ws, size_t ws_size,
                              hipStream_t stream) {
  const float* x     = (const float*)d_in[0];
  const float* mu_v0 = (const float*)d_in[1];
  const float* mu_g0 = (const float*)d_in[2];
  const float* mu_b0 = (const float*)d_in[3];
  const float* mu_v1 = (const float*)d_in[4];
  const float* mu_g1 = (const float*)d_in[5];
  const float* mu_b1 = (const float*)d_in[6];
  const float* mu_v2 = (const float*)d_in[7];
  const float* mu_g2 = (const float*)d_in[8];
  const float* mu_b2 = (const float*)d_in[9];
  const float* lv_v0 = (const float*)d_in[10];
  const float* lv_g0 = (const float*)d_in[11];
  const float* lv_b0 = (const float*)d_in[12];
  const float* lv_v1 = (const float*)d_in[13];
  const float* lv_g1 = (const float*)d_in[14];
  const float* lv_b1 = (const float*)d_in[15];
  const float* lv_v2 = (const float*)d_in[16];
  const float* lv_g2 = (const float*)d_in[17];
  const float* lv_b2 = (const float*)d_in[18];

  char* ws = (char*)d_ws;
  u16*   W1   = (u16*)(ws);                            // 4 MiB
  u16*   W0p  = (u16*)(ws + (4u << 20));               // 128 KiB
  u16*   W2   = (u16*)(ws + (4u << 20) + 131072);      // 64 KiB
  float* b0s  = (float*)(ws + (4u << 20) + 196608);    // 8 KiB
  float* b1s  = (float*)(ws + (4u << 20) + 204800);    // 8 KiB
  float* pA   = (float*)(ws + (6u << 20));             // 2 MiB
  float* pB   = (float*)(ws + (8u << 20));             // 2 MiB

  prep_all<<<512, 256, 0, stream>>>(
      mu_v0, mu_g0, mu_b0, mu_v1, mu_g1, mu_b1, mu_v2, mu_g2,
      lv_v0, lv_g0, lv_b0, lv_v1, lv_g1, lv_b1, lv_v2, lv_g2,
      W1, b1s, W0p, b0s, W2);

  for (int s = 0; s < 16; ++s) {
    const float* src = (s & 1) ? pB : pA;
    float*       dst = (s & 1) ? pA : pB;
    gemm_fused<<<512, 256, 0, stream>>>(src, dst, W1, b1s, W2, W0p, b0s,
                                        mu_b2, lv_b2, x, s == 0 ? 1 : 0);
  }
  // s=15 wrote pA
  step_final<<<128, 256, 0, stream>>>(pA, mu_b2, lv_b2, x, (float*)d_out);
}

// Round 8
// 418.076 us; speedup vs baseline: 1.5591x; 1.5591x over previous
//
#include <hip/hip_runtime.h>
#include <cstdint>
#include <cstddef>

// ---------------------------------------------------------------------------
// AFMADE block: 16-step autoregressive inversion of two 3-layer MADE MLPs.
// D=16, H=1024, B=2048. Degree-sorted hidden space (W1' block-lower-
// triangular, col-tile nt needs ktN = min(nt+2,16) K-tiles).
// R8: 64x64 GEMM tiles, 4 blocks/CU (latency overlap), XOR-swizzled LDS
// staging (conflict-free ds_read_b128), quarter-balanced nt assignment.
//   prep_all : one dispatch — bake W0'/W1'/W2' + b0s/b1s + h0 init
//   loop 16x : gemm_l1f (h1' tile + fused layer2 partial -> part)
//              step3    (reduce partials, recurrence, layer0 -> h0')
// ---------------------------------------------------------------------------

#define Dd 16
#define Hh 1024
#define Bb 2048
#define EPSV 1e-12f

typedef unsigned short u16;
typedef __attribute__((ext_vector_type(4))) float f32x4;
typedef __attribute__((ext_vector_type(8))) short s16x8;
typedef __attribute__((ext_vector_type(4))) u16 u16x4;
typedef __attribute__((ext_vector_type(8))) u16 u16x8;

__device__ __forceinline__ u16 f2bf(float f) {
  union { float f; unsigned u; } v; v.f = f;
  unsigned u = v.u;
  unsigned r = (u + 0x7fffu + ((u >> 16) & 1u)) >> 16;  // RNE
  return (u16)r;
}
__device__ __forceinline__ float bf2f(u16 u) {
  union { unsigned u; float f; } v; v.u = ((unsigned)u) << 16;
  return v.f;
}
__device__ __forceinline__ float elu(float a) {
  return a > 0.f ? a : __expf(a) - 1.f;
}
__device__ __forceinline__ void gl_lds16(const void* g, void* l) {
  __builtin_amdgcn_global_load_lds(
      (const __attribute__((address_space(1))) void*)g,
      (__attribute__((address_space(3))) void*)l, 16, 0, 0);
}

// Degree-sort permutation: group g = j%15; groups 0..3 have 69, 4..14 have 68.
__device__ __forceinline__ int p_of(int i) {
  if (i < 276) { int g = i / 69, q = i - g * 69; return g + 15 * q; }
  int r = i - 276; int g = 4 + r / 68, q = r - (g - 4) * 68;
  return g + 15 * q;
}
__device__ __forceinline__ int g_of(int i) {
  return (i < 276) ? (i / 69) : (4 + (i - 276) / 68);
}

// --------------------------- prep (one dispatch, 512 blocks) ---------------
// All blocks: one W1' row per wave (2048 rows) + h0-init slice.
// Blocks 0..7: W0'+b0s. Blocks 8..15: W2'.
__global__ __launch_bounds__(256) void prep_all(
    const float* __restrict__ mu_v0, const float* __restrict__ mu_g0,
    const float* __restrict__ mu_b0,
    const float* __restrict__ mu_v1, const float* __restrict__ mu_g1,
    const float* __restrict__ mu_b1,
    const float* __restrict__ mu_v2, const float* __restrict__ mu_g2,
    const float* __restrict__ lv_v0, const float* __restrict__ lv_g0,
    const float* __restrict__ lv_b0,
    const float* __restrict__ lv_v1, const float* __restrict__ lv_g1,
    const float* __restrict__ lv_b1,
    const float* __restrict__ lv_v2, const float* __restrict__ lv_g2,
    u16* __restrict__ W1, float* __restrict__ b1s,
    u16* __restrict__ W0, float* __restrict__ b0s,
    u16* __restrict__ W2, u16* __restrict__ h0) {
  int bid = blockIdx.x, tid = threadIdx.x;
  int l = tid & 63, w = tid >> 6;
  {  // W1' row
    int wid = bid * 4 + w;
    int net = wid >> 10, i = wid & 1023;
    int j = p_of(i), gi = g_of(i);
    const float* v = (net ? lv_v1 : mu_v1) + (size_t)j * Hh;
    float val[4][4]; float ss = 0.f;
    for (int ii = 0; ii < 4; ++ii)
      for (int t = 0; t < 4; ++t) {
        int kp = ii * 256 + 4 * l + t;
        float xx = v[p_of(kp)];
        val[ii][t] = xx; ss += xx * xx;
      }
    for (int s = 32; s; s >>= 1) ss += __shfl_xor(ss, s);
    float sc = ((net ? lv_g1 : mu_g1)[j]) * rsqrtf(ss);
    u16* o = W1 + (size_t)wid * Hh;
    for (int ii = 0; ii < 4; ++ii) {
      int k0 = ii * 256 + 4 * l;
      u16x4 wv;
      for (int t = 0; t < 4; ++t)
        wv[t] = f2bf((gi >= g_of(k0 + t)) ? sc * val[ii][t] : 0.f);
      *(u16x4*)(o + k0) = wv;
    }
    if (l == 0) b1s[wid] = (net ? lv_b1 : mu_b1)[j];
  }
  if (bid < 8) {  // W0' [2048][16] sorted rows + b0s
    int idx = bid * 256 + tid;
    int net = idx >> 10, i = idx & 1023;
    int j = p_of(i), gi = g_of(i);
    const float* v = (net ? lv_v0 : mu_v0) + j * Dd;
    float vv[16]; float ss = 0.f;
    for (int k = 0; k < 16; ++k) { vv[k] = v[k]; ss += vv[k] * vv[k]; }
    float sc = ((net ? lv_g0 : mu_g0)[j]) * rsqrtf(ss);
    u16* o = W0 + (size_t)idx * 16;
    for (int k = 0; k < 16; ++k) o[k] = f2bf((gi >= k) ? sc * vv[k] : 0.f);
    b0s[idx] = (net ? lv_b0 : mu_b0)[j];
  }
  if (bid >= 8 && bid < 16) {  // W2' rows (32)
    int wid = (bid - 8) * 4 + w;
    int net = wid >> 4, oi = wid & 15;
    const float* v = (net ? lv_v2 : mu_v2) + (size_t)oi * Hh;
    float val[4][4]; float ss = 0.f;
    for (int ii = 0; ii < 4; ++ii)
      for (int t = 0; t < 4; ++t) {
        int kp = ii * 256 + 4 * l + t;
        float xx = v[p_of(kp)];
        val[ii][t] = xx; ss += xx * xx;
      }
    for (int s = 32; s; s >>= 1) ss += __shfl_xor(ss, s);
    float sc = ((net ? lv_g2 : mu_g2)[oi]) * rsqrtf(ss);
    u16* o = W2 + (size_t)wid * Hh;
    for (int ii = 0; ii < 4; ++ii) {
      int k0 = ii * 256 + 4 * l;
      u16x4 wv;
      for (int t = 0; t < 4; ++t)
        wv[t] = f2bf((oi > g_of(k0 + t)) ? sc * val[ii][t] : 0.f);
      *(u16x4*)(o + k0) = wv;
    }
  }
  {  // h0'[net][b][i] = elu(b0[p_of(i)]); 8192 elems per block
    for (int it = 0; it < 4; ++it) {
      int e = bid * 8192 + it * 2048 + tid * 8;
      int net = e >> 21;
      int i = e & 1023;
      const float* b0 = net ? lv_b0 : mu_b0;
      u16x8 hv;
      for (int t = 0; t < 8; ++t) hv[t] = f2bf(elu(b0[p_of(i + t)]));
      *(u16x8*)(h0 + e) = hv;
    }
  }
}

// --------------------------- layer1 GEMM + fused layer2 partial ------------
// Tile 64x64, BK=64, 4 waves (2x2, wave-tile 32x32), single-buffer LDS,
// XOR-swizzled staging+reads. Grid 1024 = 4 quarters x {2 net x 32 mt x
// 4 jj}; quarter q gives nt = {jj, 15-jj, 4+jj, 11-jj}[q] (per-CU balanced,
// co-resident blocks share net+mt). ktN = min(nt+2,16).
__global__ __launch_bounds__(256, 4) void gemm_l1f(
    const u16* __restrict__ h0, const u16* __restrict__ W1,
    const float* __restrict__ b1s, const u16* __restrict__ W2,
    float* __restrict__ part) {
  __shared__ __align__(16) u16 sMem[8192];   // sA[4096] | sB[4096]; sH 64x72
  __shared__ u16 sW2b[16 * 72];
  u16* sA = sMem;
  u16* sB = sMem + 4096;

  const int bid = blockIdx.x, tid = threadIdx.x;
  const int quarter = bid >> 8, q = bid & 255;
  const int net = q >> 7, rr = q & 127;
  const int mt = rr >> 2, jj = rr & 3;
  int nt;
  switch (quarter) {
    case 0: nt = jj; break;
    case 1: nt = 15 - jj; break;
    case 2: nt = 4 + jj; break;
    default: nt = 11 - jj; break;
  }
  const int ktN = (nt + 2 < 16) ? nt + 2 : 16;
  const int m0 = mt * 64, n0 = nt * 64;
  const u16* A = h0 + (size_t)net * (Bb * Hh);
  const u16* Bm = W1 + (size_t)net * (Hh * Hh);
  const int l = tid & 63, w = tid >> 6;
  const int wr = w >> 1, wc = w & 1;     // 2x2 wave grid
  const int lr = l & 15, lk = l >> 4;
  f32x4 acc[2][2] = {};

  // W2 column tile (16 x 64) -> sW2b, stride 72
  for (int c = 0; c < 4; ++c) {
    int e = c * 256 + tid;
    int i = e >> 6, col = e & 63;
    sW2b[i * 72 + col] = W2[(size_t)(net * 16 + i) * Hh + n0 + col];
  }

  for (int kt = 0; kt < ktN; ++kt) {
    int kb = kt * 64;
    __syncthreads();                     // prev iter's reads done
    for (int c = 0; c < 2; ++c) {        // A: 512 chunks, swizzled source
      int qq = c * 256 + tid, row = qq >> 3, cc = qq & 7;
      gl_lds16(A + (size_t)(m0 + row) * Hh + kb + ((cc ^ (row & 7)) << 3),
               (char*)sA + qq * 16);
    }
    for (int c = 0; c < 2; ++c) {        // B: 512 chunks
      int qq = c * 256 + tid, row = qq >> 3, cc = qq & 7;
      gl_lds16(Bm + (size_t)(n0 + row) * Hh + kb + ((cc ^ (row & 7)) << 3),
               (char*)sB + qq * 16);
    }
    __syncthreads();                     // vmcnt drained
    for (int kk = 0; kk < 2; ++kk) {
      int cidx = kk * 4 + lk;
      s16x8 af[2], bfr[2];
      for (int mi = 0; mi < 2; ++mi) {
        int ar = wr * 32 + mi * 16 + lr;
        af[mi] = *(const s16x8*)(sA + (ar * 8 + (cidx ^ (ar & 7))) * 8);
      }
      for (int ni = 0; ni < 2; ++ni) {
        int br = wc * 32 + ni * 16 + lr;
        bfr[ni] = *(const s16x8*)(sB + (br * 8 + (cidx ^ (br & 7))) * 8);
      }
      for (int mi = 0; mi < 2; ++mi)
        for (int ni = 0; ni < 2; ++ni)
          acc[mi][ni] = __builtin_amdgcn_mfma_f32_16x16x32_bf16(
              af[mi], bfr[ni], acc[mi][ni], 0, 0, 0);
    }
  }

  // epilogue: h1 tile -> sH (stride 72), mini-GEMM vs W2 -> part
  __syncthreads();
  u16* sH = sMem;                        // 64 x 72 = 4608 u16
  for (int ni = 0; ni < 2; ++ni) {
    int col = wc * 32 + ni * 16 + lr;
    float bias = b1s[net * 1024 + n0 + col];
    for (int mi = 0; mi < 2; ++mi)
      for (int r = 0; r < 4; ++r) {
        int row = wr * 32 + mi * 16 + lk * 4 + r;
        sH[row * 72 + col] = f2bf(elu(acc[mi][ni][r] + bias));
      }
  }
  __syncthreads();
  {
    f32x4 acc2 = {};
    for (int kk = 0; kk < 2; ++kk) {
      int ko = kk * 32 + lk * 8;
      s16x8 bfr = *(const s16x8*)(sW2b + lr * 72 + ko);
      s16x8 af = *(const s16x8*)(sH + (w * 16 + lr) * 72 + ko);
      acc2 = __builtin_amdgcn_mfma_f32_16x16x32_bf16(af, bfr, acc2, 0, 0, 0);
    }
    for (int r = 0; r < 4; ++r) {
      int row = m0 + w * 16 + lk * 4 + r;
      part[((size_t)(net * Bb) + row) * 256 + nt * 16 + lr] = acc2[r];
    }
  }
}

// --------------------------- partial reduce + recur + layer0 ---------------
// 2 batch rows per block, 1024 blocks x 256 threads. (R6-validated.)
__global__ __launch_bounds__(256) void step3(
    const float* __restrict__ part,
    const float* __restrict__ b2_mu, const float* __restrict__ b2_lv,
    const u16* __restrict__ W0, const float* __restrict__ b0s,
    const float* __restrict__ x,
    u16* __restrict__ h0, float* __restrict__ out, int last) {
  __shared__ float sPart[4][260];
  __shared__ float sOut[2][32];
  __shared__ float sY[2][16];
  int tid = threadIdx.x;
  int b0g = blockIdx.x * 2;

  {
    int seg = tid >> 6, idx = (tid & 63) * 4;
    int r = seg >> 1, net = seg & 1;
    const float* src = part + ((size_t)(net * Bb) + b0g + r) * 256 + idx;
    *(f32x4*)&sPart[seg][idx] = *(const f32x4*)src;
  }
  __syncthreads();
  if (tid < 64) {
    int seg = tid >> 4, i = tid & 15;
    int r = seg >> 1, net = seg & 1;
    float s = 0.f;
    for (int ntc = 0; ntc < 16; ++ntc) s += sPart[seg][ntc * 16 + i];
    sOut[r][net * 16 + i] = s + (net ? b2_lv : b2_mu)[i];
  }
  __syncthreads();

  if (tid < 32) {
    int r = tid >> 4, d = tid & 15;
    int b = b0g + r;
    float mu = sOut[r][d];
    float ls = 0.5f * sOut[r][16 + d];
    float yn = (x[b * 16 + d] - mu) / (__expf(ls) + EPSV);
    sY[r][d] = yn;
    if (last) {
      out[b * 16 + d] = yn;
      float pp = ls;
      pp += __shfl_xor(pp, 1);
      pp += __shfl_xor(pp, 2);
      pp += __shfl_xor(pp, 4);
      pp += __shfl_xor(pp, 8);
      if (d == 0) out[Bb * 16 + b] = pp;
    }
  }
  __syncthreads();

  if (!last) {
    for (int it = 0; it < 8; ++it) {
      int jj = it * 256 + tid;      // 0..2047 sorted
      int net = jj >> 10;
      u16x8 wa = *(const u16x8*)(W0 + jj * 16);
      u16x8 wb = *(const u16x8*)(W0 + jj * 16 + 8);
      float wk[16];
      for (int tt = 0; tt < 8; ++tt) {
        wk[tt] = bf2f(wa[tt]); wk[8 + tt] = bf2f(wb[tt]);
      }
      float bias = b0s[jj];
      u16* hp = h0 + (size_t)net * (Bb * Hh) + (jj & 1023);
      for (int r = 0; r < 2; ++r) {
        float a = bias;
        for (int k = 0; k < 16; ++k) a += sY[r][k] * wk[k];
        hp[(size_t)(b0g + r) * Hh] = f2bf(elu(a));
      }
    }
  }
}

// --------------------------- launch ----------------------------------------

extern "C" void kernel_launch(void* const* d_in, const int* in_sizes, int n_in,
                              void* d_out, int out_size, void* d_ws, size_t ws_size,
                              hipStream_t stream) {
  const float* x     = (const float*)d_in[0];
  const float* mu_v0 = (const float*)d_in[1];
  const float* mu_g0 = (const float*)d_in[2];
  const float* mu_b0 = (const float*)d_in[3];
  const float* mu_v1 = (const float*)d_in[4];
  const float* mu_g1 = (const float*)d_in[5];
  const float* mu_b1 = (const float*)d_in[6];
  const float* mu_v2 = (const float*)d_in[7];
  const float* mu_g2 = (const float*)d_in[8];
  const float* mu_b2 = (const float*)d_in[9];
  const float* lv_v0 = (const float*)d_in[10];
  const float* lv_g0 = (const float*)d_in[11];
  const float* lv_b0 = (const float*)d_in[12];
  const float* lv_v1 = (const float*)d_in[13];
  const float* lv_g1 = (const float*)d_in[14];
  const float* lv_b1 = (const float*)d_in[15];
  const float* lv_v2 = (const float*)d_in[16];
  const float* lv_g2 = (const float*)d_in[17];
  const float* lv_b2 = (const float*)d_in[18];

  char* ws = (char*)d_ws;
  u16*   W1   = (u16*)(ws);                            // 4 MiB
  u16*   W0   = (u16*)(ws + (4u << 20));               // 64 KiB
  u16*   W2   = (u16*)(ws + (4u << 20) + 65536);       // 64 KiB
  float* b0s  = (float*)(ws + (4u << 20) + 131072);    // 8 KiB
  float* b1s  = (float*)(ws + (4u << 20) + 139264);    // 8 KiB
  u16*   h0   = (u16*)(ws + (4u << 20) + 147456);      // 8 MiB
  float* part = (float*)(ws + (12u << 20) + 147456);   // 4 MiB

  prep_all<<<512, 256, 0, stream>>>(
      mu_v0, mu_g0, mu_b0, mu_v1, mu_g1, mu_b1, mu_v2, mu_g2,
      lv_v0, lv_g0, lv_b0, lv_v1, lv_g1, lv_b1, lv_v2, lv_g2,
      W1, b1s, W0, b0s, W2, h0);

  for (int s = 0; s < 16; ++s) {
    gemm_l1f<<<1024, 256, 0, stream>>>(h0, W1, b1s, W2, part);
    step3<<<1024, 256, 0, stream>>>(part, mu_b2, lv_b2, W0, b0s,
                                    x, h0, (float*)d_out, s == 15 ? 1 : 0);
  }
}

// Round 9
// 358.246 us; speedup vs baseline: 1.8195x; 1.1670x over previous
//
#include <hip/hip_runtime.h>
#include <cstdint>
#include <cstddef>

// ---------------------------------------------------------------------------
// AFMADE block, incremental-exact formulation. D=16, H=1024, B=2048.
// Key fact: in degree-sorted space the MADE recurrence is strictly
// triangular: y[d] is final after step d; h0/h1 degree-groups are computed
// once (from final y prefixes) and never change. Per step s:
//   h1 group (s-1) = elu(h0[:, :Lb(s)] @ W1g^T + b1)      (K = Lb(s))
//   ML[row][:]    += h1grp @ W2g^T       (16-wide, in registers)
//   mu/lv[s] = ML[:, s] + b2;  y[s] = (x[s]-mu)/(exp(.5 lv)+eps)
//   h0 group s = elu(y[:, :16] @ W0g^T + b0)
// All state (y, ML, lsum, h0 rows) is row-local => one block owns 32 batch
// rows for the entire 16-step scan. No cross-block deps. 2 dispatches.
// Weights baked padded (groups padded to 80 units, pads ZERO so staged
// garbage is exactly masked). GEMM frags read direct from global (L2-hot).
// ---------------------------------------------------------------------------

#define Dd 16
#define Hh 1024
#define Bb 2048
#define EPSV 1e-12f

typedef unsigned short u16;
typedef __attribute__((ext_vector_type(4))) float f32x4;
typedef __attribute__((ext_vector_type(8))) short s16x8;
typedef __attribute__((ext_vector_type(4))) u16 u16x4;

__device__ __forceinline__ u16 f2bf(float f) {
  union { float f; unsigned u; } v; v.f = f;
  unsigned u = v.u;
  unsigned r = (u + 0x7fffu + ((u >> 16) & 1u)) >> 16;  // RNE
  return (u16)r;
}
__device__ __forceinline__ float elu(float a) {
  return a > 0.f ? a : __expf(a) - 1.f;
}

// Degree-sort permutation: group g = j%15; groups 0..3 have 69, 4..14 have 68.
__device__ __forceinline__ int p_of(int i) {
  if (i < 276) { int g = i / 69, q = i - g * 69; return g + 15 * q; }
  int r = i - 276; int g = 4 + r / 68, q = r - (g - 4) * 68;
  return g + 15 * q;
}
__device__ __forceinline__ int g_of(int i) {
  return (i < 276) ? (i / 69) : (4 + (i - 276) / 68);
}
__device__ __forceinline__ int lb_of(int g) {            // prefix length
  return (g <= 4) ? 69 * g : 276 + 68 * (g - 4);
}
__device__ __forceinline__ int sz_of(int g) { return (g < 4) ? 69 : 68; }

// Padded layouts (all pads baked ZERO):
//  W1p[net][15][80][1024] bf16   (group rows padded to 80)
//  W2p[net][15][16][104]  bf16   (K = units padded to 104, cols>=sz zero)
//  W0p[net][15][80][32]   bf16   (K = 16 y-dims padded to 32)
//  b1p/b0p[net][15][80]   f32    (pads zero)
#define W1P_NET (15 * 80 * 1024)
#define W2P_NET (15 * 16 * 104)
#define W0P_NET (15 * 80 * 32)

// --------------------------- prep (one dispatch, 600 blocks) ---------------
__global__ __launch_bounds__(256) void prep_all(
    const float* __restrict__ mu_v0, const float* __restrict__ mu_g0,
    const float* __restrict__ mu_b0,
    const float* __restrict__ mu_v1, const float* __restrict__ mu_g1,
    const float* __restrict__ mu_b1,
    const float* __restrict__ mu_v2, const float* __restrict__ mu_g2,
    const float* __restrict__ lv_v0, const float* __restrict__ lv_g0,
    const float* __restrict__ lv_b0,
    const float* __restrict__ lv_v1, const float* __restrict__ lv_g1,
    const float* __restrict__ lv_b1,
    const float* __restrict__ lv_v2, const float* __restrict__ lv_g2,
    u16* __restrict__ W1p, u16* __restrict__ W2p, u16* __restrict__ W0p,
    float* __restrict__ b1p, float* __restrict__ b0p) {
  int bid = blockIdx.x, tid = threadIdx.x;
  int l = tid & 63, w = tid >> 6;

  {  // W1p: one wave per padded row; wid = net*1200 + g*80 + u
    int wid = bid * 4 + w;                 // 0..2399
    int net = wid / 1200, rem = wid % 1200;
    int g = rem / 80, u = rem % 80;
    u16* o = W1p + (size_t)wid * 1024;
    if (u < sz_of(g)) {
      int j = p_of(lb_of(g) + u);
      const float* v = (net ? lv_v1 : mu_v1) + (size_t)j * Hh;
      float val[4][4]; float ss = 0.f;
      for (int ii = 0; ii < 4; ++ii)
        for (int t = 0; t < 4; ++t) {
          int kp = ii * 256 + 4 * l + t;
          float xx = v[p_of(kp)];
          val[ii][t] = xx; ss += xx * xx;
        }
      for (int s = 32; s; s >>= 1) ss += __shfl_xor(ss, s);
      float sc = ((net ? lv_g1 : mu_g1)[j]) * rsqrtf(ss);
      for (int ii = 0; ii < 4; ++ii) {
        int k0 = ii * 256 + 4 * l;
        u16x4 wv;
        for (int t = 0; t < 4; ++t)
          wv[t] = f2bf((g >= g_of(k0 + t)) ? sc * val[ii][t] : 0.f);
        *(u16x4*)(o + k0) = wv;
      }
    } else {
      u16x4 z = {0, 0, 0, 0};
      for (int ii = 0; ii < 4; ++ii) *(u16x4*)(o + ii * 256 + 4 * l) = z;
    }
  }

  if (bid < 8) {  // W2p: one wave per (net, out-row)
    int wid2 = bid * 4 + w;                // 0..31
    int nn = wid2 >> 4, oi = wid2 & 15;
    const float* v = (nn ? lv_v2 : mu_v2) + (size_t)oi * Hh;
    float ss = 0.f;
    for (int ii = 0; ii < 4; ++ii) {
      f32x4 vv = *(const f32x4*)(v + ii * 256 + 4 * l);
      ss += vv[0]*vv[0] + vv[1]*vv[1] + vv[2]*vv[2] + vv[3]*vv[3];
    }
    for (int s = 32; s; s >>= 1) ss += __shfl_xor(ss, s);
    float sc = ((nn ? lv_g2 : mu_g2)[oi]) * rsqrtf(ss);
    for (int e = l; e < 15 * 104; e += 64) {
      int g = e / 104, u = e % 104;
      float val = 0.f;
      if (u < sz_of(g) && oi > g) val = sc * v[p_of(lb_of(g) + u)];
      W2p[nn * W2P_NET + g * (16 * 104) + oi * 104 + u] = f2bf(val);
    }
  }

  if (bid >= 8 && bid < 18) {  // W0p + b0p + b1p: one thread per padded unit
    int idx = (bid - 8) * 256 + tid;       // 0..2559
    if (idx < 2400) {
      int nn = idx / 1200, rem = idx % 1200;
      int g = rem / 80, u = rem % 80;
      u16* orow = W0p + nn * W0P_NET + g * (80 * 32) + u * 32;
      if (u < sz_of(g)) {
        int j = p_of(lb_of(g) + u);
        const float* v = (nn ? lv_v0 : mu_v0) + j * Dd;
        float vv[16]; float ss = 0.f;
        for (int k = 0; k < 16; ++k) { vv[k] = v[k]; ss += vv[k] * vv[k]; }
        float sc = ((nn ? lv_g0 : mu_g0)[j]) * rsqrtf(ss);
        for (int k = 0; k < 16; ++k)
          orow[k] = f2bf((g >= k) ? sc * vv[k] : 0.f);
        for (int k = 16; k < 32; ++k) orow[k] = 0;
        b0p[nn * 1200 + g * 80 + u] = (nn ? lv_b0 : mu_b0)[j];
        b1p[nn * 1200 + g * 80 + u] = (nn ? lv_b1 : mu_b1)[j];
      } else {
        for (int k = 0; k < 32; ++k) orow[k] = 0;
        b0p[nn * 1200 + g * 80 + u] = 0.f;
        b1p[nn * 1200 + g * 80 + u] = 0.f;
      }
    }
  }
}

// --------------------------- main (one dispatch, 64 blocks) ----------------
// Block owns 32 batch rows; 4 waves = (net, rowhalf); runs all 16 steps.
__global__ __launch_bounds__(256) void afmade_main(
    const u16* __restrict__ W1p, const u16* __restrict__ W2p,
    const u16* __restrict__ W0p,
    const float* __restrict__ b1p, const float* __restrict__ b0p,
    const float* __restrict__ b2_mu, const float* __restrict__ b2_lv,
    const float* __restrict__ x, u16* __restrict__ h0p,
    float* __restrict__ out) {
  __shared__ u16 sH1[2][32][104];   // h1 group tile (units 80..95 stay zero)
  __shared__ u16 yb[32][40];        // y bf16, cols 16..39 stay zero
  __shared__ float sX[32][16];
  __shared__ float sMLex[2][32];
  __shared__ float sLsum[32];

  const int tid = threadIdx.x;
  const int l = tid & 63, w = tid >> 6;
  const int net = w >> 1, rh = w & 1;
  const int lr = l & 15, lk = l >> 4;
  const int b0g = blockIdx.x * 32;

  for (int e = tid; e < 512; e += 256) {
    int r = e >> 4, d = e & 15;
    sX[r][d] = x[(size_t)(b0g + r) * 16 + d];
  }
  for (int e = tid; e < 32 * 40; e += 256) ((u16*)yb)[e] = 0;
  for (int e = tid; e < 2 * 32 * 104; e += 256) ((u16*)sH1)[e] = 0;
  if (tid < 32) sLsum[tid] = 0.f;
  f32x4 mlacc = {0.f, 0.f, 0.f, 0.f};
  __syncthreads();

  const u16* W1n = W1p + (size_t)net * W1P_NET;
  const u16* W2n = W2p + net * W2P_NET;
  const u16* W0n = W0p + net * W0P_NET;
  u16* h0n = h0p + (size_t)net * (Bb * Hh);
  const int arow = b0g + rh * 16 + lr;   // global batch row for A-frags
  const int drow = rh * 16 + lk * 4;     // local D-row base (+reg)

  for (int s = 0; s < 16; ++s) {
    if (s > 0) {
      const int g = s - 1;
      const int Kb = lb_of(s);           // real K
      const int ktn = (Kb + 63) >> 6;
      const u16* Wg = W1n + g * (80 * 1024);
      f32x4 h1acc[5] = {};
      for (int kt = 0; kt < ktn; ++kt) {
        int kb = kt * 64;
#pragma unroll
        for (int kk = 0; kk < 2; ++kk) {
          int ko = kb + kk * 32 + lk * 8;
          s16x8 af = *(const s16x8*)(h0n + (size_t)arow * Hh + ko);
#pragma unroll
          for (int nf = 0; nf < 5; ++nf) {
            s16x8 bfr = *(const s16x8*)(Wg + (nf * 16 + lr) * 1024 + ko);
            h1acc[nf] = __builtin_amdgcn_mfma_f32_16x16x32_bf16(
                af, bfr, h1acc[nf], 0, 0, 0);
          }
        }
      }
      // h1 = elu(acc + b1) -> sH1 (D-layout: col=lane&15 -> unit)
#pragma unroll
      for (int nf = 0; nf < 5; ++nf) {
        int unit = nf * 16 + lr;
        float bias = b1p[net * 1200 + g * 80 + unit];
#pragma unroll
        for (int reg = 0; reg < 4; ++reg)
          sH1[net][drow + reg][unit] = f2bf(elu(h1acc[nf][reg] + bias));
      }
      __syncthreads();
      // ML += h1 @ W2g^T   (K = 96: units 80..95 zero on BOTH sides)
      const u16* W2g = W2n + g * (16 * 104);
#pragma unroll
      for (int c = 0; c < 3; ++c) {
        s16x8 a = *(const s16x8*)(&sH1[net][rh * 16 + lr][c * 32 + lk * 8]);
        s16x8 b = *(const s16x8*)(W2g + lr * 104 + c * 32 + lk * 8);
        mlacc = __builtin_amdgcn_mfma_f32_16x16x32_bf16(a, b, mlacc, 0, 0, 0);
      }
    }
    // extract mu/lv column s
    __syncthreads();
    if (lr == s) {
#pragma unroll
      for (int reg = 0; reg < 4; ++reg) sMLex[net][drow + reg] = mlacc[reg];
    }
    __syncthreads();
    if (tid < 32) {
      int r = tid;
      float mu = sMLex[0][r] + b2_mu[s];
      float lv = sMLex[1][r] + b2_lv[s];
      float ls = 0.5f * lv;
      float yv = (sX[r][s] - mu) / (__expf(ls) + EPSV);
      out[(size_t)(b0g + r) * 16 + s] = yv;
      yb[r][s] = f2bf(yv);
      float ns = sLsum[r] + ls;
      sLsum[r] = ns;
      if (s == 15) out[Bb * 16 + b0g + r] = ns;
    }
    __syncthreads();
    if (s < 15) {
      // h0 group s = elu(y @ W0g^T + b0); y cols > s masked by W0p zeros
      const int LbS = lb_of(s);
      const int szS = sz_of(s);
      const u16* W0g = W0n + s * (80 * 32);
      s16x8 yfrag = *(const s16x8*)(&yb[rh * 16 + lr][lk * 8]);
#pragma unroll
      for (int nf = 0; nf < 5; ++nf) {
        int unit = nf * 16 + lr;
        s16x8 wfrag = *(const s16x8*)(W0g + unit * 32 + lk * 8);
        f32x4 h = __builtin_amdgcn_mfma_f32_16x16x32_bf16(
            yfrag, wfrag, (f32x4){0.f, 0.f, 0.f, 0.f}, 0, 0, 0);
        if (unit < szS) {
          float bias = b0p[net * 1200 + s * 80 + unit];
#pragma unroll
          for (int reg = 0; reg < 4; ++reg)
            h0n[(size_t)(b0g + drow + reg) * Hh + LbS + unit] =
                f2bf(elu(h[reg] + bias));
        }
      }
      __syncthreads();  // h0p stores drained before next step's A-loads
    }
  }
}

// --------------------------- launch ----------------------------------------

extern "C" void kernel_launch(void* const* d_in, const int* in_sizes, int n_in,
                              void* d_out, int out_size, void* d_ws, size_t ws_size,
                              hipStream_t stream) {
  const float* x     = (const float*)d_in[0];
  const float* mu_v0 = (const float*)d_in[1];
  const float* mu_g0 = (const float*)d_in[2];
  const float* mu_b0 = (const float*)d_in[3];
  const float* mu_v1 = (const float*)d_in[4];
  const float* mu_g1 = (const float*)d_in[5];
  const float* mu_b1 = (const float*)d_in[6];
  const float* mu_v2 = (const float*)d_in[7];
  const float* mu_g2 = (const float*)d_in[8];
  const float* mu_b2 = (const float*)d_in[9];
  const float* lv_v0 = (const float*)d_in[10];
  const float* lv_g0 = (const float*)d_in[11];
  const float* lv_b0 = (const float*)d_in[12];
  const float* lv_v1 = (const float*)d_in[13];
  const float* lv_g1 = (const float*)d_in[14];
  const float* lv_b1 = (const float*)d_in[15];
  const float* lv_v2 = (const float*)d_in[16];
  const float* lv_g2 = (const float*)d_in[17];
  const float* lv_b2 = (const float*)d_in[18];

  char* ws = (char*)d_ws;
  u16*   W1p = (u16*)(ws);                       // 4,915,200 B
  u16*   W2p = (u16*)(ws + 4915200);             //    99,840 B
  u16*   W0p = (u16*)(ws + 5015040);             //   153,600 B
  float* b1p = (float*)(ws + 5168640);           //     9,600 B
  float* b0p = (float*)(ws + 5178240);           //     9,600 B
  u16*   h0p = (u16*)(ws + 5187840);             // 8,388,608 B

  prep_all<<<600, 256, 0, stream>>>(
      mu_v0, mu_g0, mu_b0, mu_v1, mu_g1, mu_b1, mu_v2, mu_g2,
      lv_v0, lv_g0, lv_b0, lv_v1, lv_g1, lv_b1, lv_v2, lv_g2,
      W1p, W2p, W0p, b1p, b0p);

  afmade_main<<<64, 256, 0, stream>>>(W1p, W2p, W0p, b1p, b0p,
                                      mu_b2, lv_b2, x, h0p, (float*)d_out);
}

// Round 10
// 131.390 us; speedup vs baseline: 4.9610x; 2.7266x over previous
//
#include <hip/hip_runtime.h>
#include <cstdint>
#include <cstddef>

// ---------------------------------------------------------------------------
// AFMADE block, incremental-exact formulation. D=16, H=1024, B=2048.
// Degree-sorted space: y[d] final after step d; h0/h1 degree-groups computed
// once. Per step s: h1 group s-1 (K=Lb(s)) -> ML += @W2g -> mu/lv[s] ->
// y[s] -> h0 group s. All state row-local.
// R10: 16 rows/block (128 blocks, half GPU), 8 waves = (net, kq) with 4-way
// K-split + LDS partial reduce; h0 kept entirely in LDS (no global h0).
// 2 dispatches.
// ---------------------------------------------------------------------------

#define Dd 16
#define Hh 1024
#define Bb 2048
#define EPSV 1e-12f

typedef unsigned short u16;
typedef __attribute__((ext_vector_type(4))) float f32x4;
typedef __attribute__((ext_vector_type(8))) short s16x8;
typedef __attribute__((ext_vector_type(4))) u16 u16x4;
typedef __attribute__((ext_vector_type(8))) u16 u16x8;

__device__ __forceinline__ u16 f2bf(float f) {
  union { float f; unsigned u; } v; v.f = f;
  unsigned u = v.u;
  unsigned r = (u + 0x7fffu + ((u >> 16) & 1u)) >> 16;  // RNE
  return (u16)r;
}
__device__ __forceinline__ float elu(float a) {
  return a > 0.f ? a : __expf(a) - 1.f;
}

// Degree-sort permutation: group g = j%15; groups 0..3 have 69, 4..14 have 68.
__device__ __forceinline__ int p_of(int i) {
  if (i < 276) { int g = i / 69, q = i - g * 69; return g + 15 * q; }
  int r = i - 276; int g = 4 + r / 68, q = r - (g - 4) * 68;
  return g + 15 * q;
}
__device__ __forceinline__ int g_of(int i) {
  return (i < 276) ? (i / 69) : (4 + (i - 276) / 68);
}
__device__ __forceinline__ int lb_of(int g) {            // prefix length
  return (g <= 4) ? 69 * g : 276 + 68 * (g - 4);
}
__device__ __forceinline__ int sz_of(int g) { return (g < 4) ? 69 : 68; }

// Padded layouts (all pads baked ZERO):
//  W1p[net][15][80][1024] bf16, W2p[net][15][16][104] bf16,
//  W0p[net][15][80][32] bf16, b1p/b0p[net][15][80] f32.
#define W1P_NET (15 * 80 * 1024)
#define W2P_NET (15 * 16 * 104)
#define W0P_NET (15 * 80 * 32)

// --------------------------- prep (one dispatch, 600 blocks) ---------------
__global__ __launch_bounds__(256) void prep_all(
    const float* __restrict__ mu_v0, const float* __restrict__ mu_g0,
    const float* __restrict__ mu_b0,
    const float* __restrict__ mu_v1, const float* __restrict__ mu_g1,
    const float* __restrict__ mu_b1,
    const float* __restrict__ mu_v2, const float* __restrict__ mu_g2,
    const float* __restrict__ lv_v0, const float* __restrict__ lv_g0,
    const float* __restrict__ lv_b0,
    const float* __restrict__ lv_v1, const float* __restrict__ lv_g1,
    const float* __restrict__ lv_b1,
    const float* __restrict__ lv_v2, const float* __restrict__ lv_g2,
    u16* __restrict__ W1p, u16* __restrict__ W2p, u16* __restrict__ W0p,
    float* __restrict__ b1p, float* __restrict__ b0p) {
  int bid = blockIdx.x, tid = threadIdx.x;
  int l = tid & 63, w = tid >> 6;

  {  // W1p: one wave per padded row; wid = net*1200 + g*80 + u
    int wid = bid * 4 + w;                 // 0..2399
    int net = wid / 1200, rem = wid % 1200;
    int g = rem / 80, u = rem % 80;
    u16* o = W1p + (size_t)wid * 1024;
    if (u < sz_of(g)) {
      int j = p_of(lb_of(g) + u);
      const float* v = (net ? lv_v1 : mu_v1) + (size_t)j * Hh;
      float val[4][4]; float ss = 0.f;
      for (int ii = 0; ii < 4; ++ii)
        for (int t = 0; t < 4; ++t) {
          int kp = ii * 256 + 4 * l + t;
          float xx = v[p_of(kp)];
          val[ii][t] = xx; ss += xx * xx;
        }
      for (int s = 32; s; s >>= 1) ss += __shfl_xor(ss, s);
      float sc = ((net ? lv_g1 : mu_g1)[j]) * rsqrtf(ss);
      for (int ii = 0; ii < 4; ++ii) {
        int k0 = ii * 256 + 4 * l;
        u16x4 wv;
        for (int t = 0; t < 4; ++t)
          wv[t] = f2bf((g >= g_of(k0 + t)) ? sc * val[ii][t] : 0.f);
        *(u16x4*)(o + k0) = wv;
      }
    } else {
      u16x4 z = {0, 0, 0, 0};
      for (int ii = 0; ii < 4; ++ii) *(u16x4*)(o + ii * 256 + 4 * l) = z;
    }
  }

  if (bid < 8) {  // W2p: one wave per (net, out-row)
    int wid2 = bid * 4 + w;                // 0..31
    int nn = wid2 >> 4, oi = wid2 & 15;
    const float* v = (nn ? lv_v2 : mu_v2) + (size_t)oi * Hh;
    float ss = 0.f;
    for (int ii = 0; ii < 4; ++ii) {
      f32x4 vv = *(const f32x4*)(v + ii * 256 + 4 * l);
      ss += vv[0]*vv[0] + vv[1]*vv[1] + vv[2]*vv[2] + vv[3]*vv[3];
    }
    for (int s = 32; s; s >>= 1) ss += __shfl_xor(ss, s);
    float sc = ((nn ? lv_g2 : mu_g2)[oi]) * rsqrtf(ss);
    for (int e = l; e < 15 * 104; e += 64) {
      int g = e / 104, u = e % 104;
      float val = 0.f;
      if (u < sz_of(g) && oi > g) val = sc * v[p_of(lb_of(g) + u)];
      W2p[nn * W2P_NET + g * (16 * 104) + oi * 104 + u] = f2bf(val);
    }
  }

  if (bid >= 8 && bid < 18) {  // W0p + b0p + b1p: one thread per padded unit
    int idx = (bid - 8) * 256 + tid;       // 0..2559
    if (idx < 2400) {
      int nn = idx / 1200, rem = idx % 1200;
      int g = rem / 80, u = rem % 80;
      u16* orow = W0p + nn * W0P_NET + g * (80 * 32) + u * 32;
      if (u < sz_of(g)) {
        int j = p_of(lb_of(g) + u);
        const float* v = (nn ? lv_v0 : mu_v0) + j * Dd;
        float vv[16]; float ss = 0.f;
        for (int k = 0; k < 16; ++k) { vv[k] = v[k]; ss += vv[k] * vv[k]; }
        float sc = ((nn ? lv_g0 : mu_g0)[j]) * rsqrtf(ss);
        for (int k = 0; k < 16; ++k)
          orow[k] = f2bf((g >= k) ? sc * vv[k] : 0.f);
        for (int k = 16; k < 32; ++k) orow[k] = 0;
        b0p[nn * 1200 + g * 80 + u] = (nn ? lv_b0 : mu_b0)[j];
        b1p[nn * 1200 + g * 80 + u] = (nn ? lv_b1 : mu_b1)[j];
      } else {
        for (int k = 0; k < 32; ++k) orow[k] = 0;
        b0p[nn * 1200 + g * 80 + u] = 0.f;
        b1p[nn * 1200 + g * 80 + u] = 0.f;
      }
    }
  }
}

// --------------------------- main (one dispatch, 128 blocks) ---------------
// Block owns 16 rows; 8 waves = (net, kq). h0 in LDS. 4-way K-split.
__global__ __launch_bounds__(512) void afmade_main(
    const u16* __restrict__ W1p, const u16* __restrict__ W2p,
    const u16* __restrict__ W0p,
    const float* __restrict__ b1p, const float* __restrict__ b0p,
    const float* __restrict__ b2_mu, const float* __restrict__ b2_lv,
    const float* __restrict__ x, float* __restrict__ out) {
  __shared__ u16 h0L[2][16][1032];        // 66048 B (pad +8: 2-way banks)
  __shared__ float sPart[2][4][16][80];   // 40960 B
  __shared__ u16 sH1[2][16][104];         // 6656 B (units 80..95 stay zero)
  __shared__ u16 yb[16][40];              // cols 16..31 stay zero
  __shared__ float sX[16][16];
  __shared__ float sMLex[2][16];
  __shared__ float sLsum[16];

  const int tid = threadIdx.x;
  const int l = tid & 63, w = tid >> 6;
  const int net = w >> 2, kq = w & 3;
  const int lr = l & 15, lk = l >> 4;
  const int b0g = blockIdx.x * 16;

  // zero-init LDS state (h0L zeros make masked-weight products exact)
  {
    u16x8 z = {0, 0, 0, 0, 0, 0, 0, 0};
    for (int e = tid; e < 4128; e += 512) ((u16x8*)h0L)[e] = z;
    for (int e = tid; e < 416; e += 512) ((u16x8*)sH1)[e] = z;
    for (int e = tid; e < 80; e += 512) ((u16x8*)yb)[e] = z;
  }
  for (int e = tid; e < 256; e += 512)
    sX[e >> 4][e & 15] = x[(size_t)(b0g + (e >> 4)) * 16 + (e & 15)];
  if (tid < 16) sLsum[tid] = 0.f;
  f32x4 mlacc = {0.f, 0.f, 0.f, 0.f};    // live on kq==0 waves
  __syncthreads();

  const u16* W1n = W1p + (size_t)net * W1P_NET;
  const u16* W2n = W2p + net * W2P_NET;
  const u16* W0n = W0p + net * W0P_NET;

  for (int s = 0; s < 16; ++s) {
    if (s > 0) {
      const int g = s - 1;
      const int ktn = (lb_of(s) + 63) >> 6;
      const u16* Wg = W1n + g * (80 * 1024);
      f32x4 hacc[5] = {};
      for (int kt = kq; kt < ktn; kt += 4) {
        int kb = kt * 64;
        const u16* ar = &h0L[net][lr][kb];
        s16x8 a0 = *(const s16x8*)(ar + lk * 8);
        s16x8 a1 = *(const s16x8*)(ar + 32 + lk * 8);
        const u16* bp = Wg + lr * 1024 + kb + lk * 8;
        s16x8 b00 = *(const s16x8*)(bp);
        s16x8 b01 = *(const s16x8*)(bp + 16 * 1024);
        s16x8 b02 = *(const s16x8*)(bp + 32 * 1024);
        s16x8 b03 = *(const s16x8*)(bp + 48 * 1024);
        s16x8 b04 = *(const s16x8*)(bp + 64 * 1024);
        s16x8 b10 = *(const s16x8*)(bp + 32);
        s16x8 b11 = *(const s16x8*)(bp + 16 * 1024 + 32);
        s16x8 b12 = *(const s16x8*)(bp + 32 * 1024 + 32);
        s16x8 b13 = *(const s16x8*)(bp + 48 * 1024 + 32);
        s16x8 b14 = *(const s16x8*)(bp + 64 * 1024 + 32);
        hacc[0] = __builtin_amdgcn_mfma_f32_16x16x32_bf16(a0, b00, hacc[0], 0, 0, 0);
        hacc[1] = __builtin_amdgcn_mfma_f32_16x16x32_bf16(a0, b01, hacc[1], 0, 0, 0);
        hacc[2] = __builtin_amdgcn_mfma_f32_16x16x32_bf16(a0, b02, hacc[2], 0, 0, 0);
        hacc[3] = __builtin_amdgcn_mfma_f32_16x16x32_bf16(a0, b03, hacc[3], 0, 0, 0);
        hacc[4] = __builtin_amdgcn_mfma_f32_16x16x32_bf16(a0, b04, hacc[4], 0, 0, 0);
        hacc[0] = __builtin_amdgcn_mfma_f32_16x16x32_bf16(a1, b10, hacc[0], 0, 0, 0);
        hacc[1] = __builtin_amdgcn_mfma_f32_16x16x32_bf16(a1, b11, hacc[1], 0, 0, 0);
        hacc[2] = __builtin_amdgcn_mfma_f32_16x16x32_bf16(a1, b12, hacc[2], 0, 0, 0);
        hacc[3] = __builtin_amdgcn_mfma_f32_16x16x32_bf16(a1, b13, hacc[3], 0, 0, 0);
        hacc[4] = __builtin_amdgcn_mfma_f32_16x16x32_bf16(a1, b14, hacc[4], 0, 0, 0);
      }
#pragma unroll
      for (int nf = 0; nf < 5; ++nf)
#pragma unroll
        for (int reg = 0; reg < 4; ++reg)
          sPart[net][kq][lk * 4 + reg][nf * 16 + lr] = hacc[nf][reg];
      __syncthreads();
      // reduce 4 partials + bias + elu -> sH1 (2560 outputs, 5/thread)
      for (int c = 0; c < 5; ++c) {
        int idx = c * 512 + tid;
        int nn = idx >> 11;                 // /1280? 2560=2*1280; use div
        nn = idx / 1280;
        int rem = idx - nn * 1280;
        int rr = rem / 80, uu = rem - rr * 80;
        float v = sPart[nn][0][rr][uu] + sPart[nn][1][rr][uu] +
                  sPart[nn][2][rr][uu] + sPart[nn][3][rr][uu] +
                  b1p[nn * 1200 + g * 80 + uu];
        sH1[nn][rr][uu] = f2bf(elu(v));
      }
      __syncthreads();
      // ML += h1grp @ W2g^T (K=96; pads zero both sides) — kq==0 waves
      if (kq == 0) {
        const u16* W2g = W2n + g * (16 * 104);
#pragma unroll
        for (int c = 0; c < 3; ++c) {
          s16x8 a = *(const s16x8*)(&sH1[net][lr][c * 32 + lk * 8]);
          s16x8 b = *(const s16x8*)(W2g + lr * 104 + c * 32 + lk * 8);
          mlacc = __builtin_amdgcn_mfma_f32_16x16x32_bf16(a, b, mlacc, 0, 0, 0);
        }
      }
    }
    // extract mu/lv column s (kq==0 waves hold mlacc)
    if (kq == 0 && lr == s) {
#pragma unroll
      for (int reg = 0; reg < 4; ++reg) sMLex[net][lk * 4 + reg] = mlacc[reg];
    }
    __syncthreads();
    if (tid < 16) {
      int r = tid;
      float mu = sMLex[0][r] + b2_mu[s];
      float lv = sMLex[1][r] + b2_lv[s];
      float ls = 0.5f * lv;
      float yv = (sX[r][s] - mu) / (__expf(ls) + EPSV);
      out[(size_t)(b0g + r) * 16 + s] = yv;
      yb[r][s] = f2bf(yv);
      float ns = sLsum[r] + ls;
      sLsum[r] = ns;
      if (s == 15) out[Bb * 16 + b0g + r] = ns;
    }
    __syncthreads();
    if (s < 15) {
      // h0 group s = elu(y @ W0g^T + b0) -> h0L
      const int LbS = lb_of(s), szS = sz_of(s);
      const u16* W0g = W0n + s * (80 * 32);
      s16x8 yfrag = *(const s16x8*)(&yb[lr][lk * 8]);
#pragma unroll
      for (int t = 0; t < 2; ++t) {
        int nf = kq + t * 4;
        if (nf < 5) {
          int unit = nf * 16 + lr;
          s16x8 wf = *(const s16x8*)(W0g + unit * 32 + lk * 8);
          f32x4 h = __builtin_amdgcn_mfma_f32_16x16x32_bf16(
              yfrag, wf, (f32x4){0.f, 0.f, 0.f, 0.f}, 0, 0, 0);
          if (unit < szS) {
            float bias = b0p[net * 1200 + s * 80 + unit];
#pragma unroll
            for (int reg = 0; reg < 4; ++reg)
              h0L[net][lk * 4 + reg][LbS + unit] = f2bf(elu(h[reg] + bias));
          }
        }
      }
      __syncthreads();   // h0L stable before next step's A-reads
    }
  }
}

// --------------------------- launch ----------------------------------------

extern "C" void kernel_launch(void* const* d_in, const int* in_sizes, int n_in,
                              void* d_out, int out_size, void* d_ws, size_t ws_size,
                              hipStream_t stream) {
  const float* x     = (const float*)d_in[0];
  const float* mu_v0 = (const float*)d_in[1];
  const float* mu_g0 = (const float*)d_in[2];
  const float* mu_b0 = (const float*)d_in[3];
  const float* mu_v1 = (const float*)d_in[4];
  const float* mu_g1 = (const float*)d_in[5];
  const float* mu_b1 = (const float*)d_in[6];
  const float* mu_v2 = (const float*)d_in[7];
  const float* mu_g2 = (const float*)d_in[8];
  const float* mu_b2 = (const float*)d_in[9];
  const float* lv_v0 = (const float*)d_in[10];
  const float* lv_g0 = (const float*)d_in[11];
  const float* lv_b0 = (const float*)d_in[12];
  const float* lv_v1 = (const float*)d_in[13];
  const float* lv_g1 = (const float*)d_in[14];
  const float* lv_b1 = (const float*)d_in[15];
  const float* lv_v2 = (const float*)d_in[16];
  const float* lv_g2 = (const float*)d_in[17];
  const float* lv_b2 = (const float*)d_in[18];

  char* ws = (char*)d_ws;
  u16*   W1p = (u16*)(ws);                       // 4,915,200 B
  u16*   W2p = (u16*)(ws + 4915200);             //    99,840 B
  u16*   W0p = (u16*)(ws + 5015040);             //   153,600 B
  float* b1p = (float*)(ws + 5168640);           //     9,600 B
  float* b0p = (float*)(ws + 5178240);           //     9,600 B

  prep_all<<<600, 256, 0, stream>>>(
      mu_v0, mu_g0, mu_b0, mu_v1, mu_g1, mu_b1, mu_v2, mu_g2,
      lv_v0, lv_g0, lv_b0, lv_v1, lv_g1, lv_b1, lv_v2, lv_g2,
      W1p, W2p, W0p, b1p, b0p);

  afmade_main<<<128, 512, 0, stream>>>(W1p, W2p, W0p, b1p, b0p,
                                       mu_b2, lv_b2, x, (float*)d_out);
}

// Round 11
// 112.715 us; speedup vs baseline: 5.7830x; 1.1657x over previous
//
#include <hip/hip_runtime.h>
#include <cstdint>
#include <cstddef>

// ---------------------------------------------------------------------------
// AFMADE block, incremental-exact formulation. D=16, H=1024, B=2048.
// Degree-sorted space: y[d] final after step d; h0/h1 degree-groups computed
// once. Per step s: h1 group s-1 (K=Lb(s)) -> ML += @W2g -> mu/lv[s] ->
// y[s] -> h0 group s. All state row-local; block owns 16 rows for the scan.
// R11: W1 baked into per-wave MFMA fragment order (W1f) so every B-load is
// one contiguous 1KB dwordx4 (was 16-segment scatter). Biases/b2 in LDS.
// ML(both nets)+y fused into wave 0 => 4 barriers/step. 3 dispatches.
// ---------------------------------------------------------------------------

#define Dd 16
#define Hh 1024
#define Bb 2048
#define EPSV 1e-12f

typedef unsigned short u16;
typedef __attribute__((ext_vector_type(4))) float f32x4;
typedef __attribute__((ext_vector_type(8))) short s16x8;
typedef __attribute__((ext_vector_type(4))) u16 u16x4;
typedef __attribute__((ext_vector_type(8))) u16 u16x8;

__device__ __forceinline__ u16 f2bf(float f) {
  union { float f; unsigned u; } v; v.f = f;
  unsigned u = v.u;
  unsigned r = (u + 0x7fffu + ((u >> 16) & 1u)) >> 16;  // RNE
  return (u16)r;
}
__device__ __forceinline__ float elu(float a) {
  return a > 0.f ? a : __expf(a) - 1.f;
}

// Degree-sort permutation: group g = j%15; groups 0..3 have 69, 4..14 have 68.
__device__ __forceinline__ int p_of(int i) {
  if (i < 276) { int g = i / 69, q = i - g * 69; return g + 15 * q; }
  int r = i - 276; int g = 4 + r / 68, q = r - (g - 4) * 68;
  return g + 15 * q;
}
__device__ __forceinline__ int g_of(int i) {
  return (i < 276) ? (i / 69) : (4 + (i - 276) / 68);
}
__device__ __forceinline__ int lb_of(int g) {            // prefix length
  return (g <= 4) ? 69 * g : 276 + 68 * (g - 4);
}
__device__ __forceinline__ int sz_of(int g) { return (g < 4) ? 69 : 68; }

// Padded layouts (all pads baked ZERO):
//  W1p[net][15][80][1024] bf16 (linear, input to prep_w1f)
//  W1f[net][15][16 kt][5 nf][2 kk][64 lane][8] bf16 (fragment order)
//  W2p[net][15][16][104] bf16, W0p[net][15][80][32] bf16,
//  b1p/b0p[net][15][80] f32.
#define W1P_NET (15 * 80 * 1024)
#define W2P_NET (15 * 16 * 104)
#define W0P_NET (15 * 80 * 32)

// --------------------------- prep (one dispatch, 600 blocks) ---------------
__global__ __launch_bounds__(256) void prep_all(
    const float* __restrict__ mu_v0, const float* __restrict__ mu_g0,
    const float* __restrict__ mu_b0,
    const float* __restrict__ mu_v1, const float* __restrict__ mu_g1,
    const float* __restrict__ mu_b1,
    const float* __restrict__ mu_v2, const float* __restrict__ mu_g2,
    const float* __restrict__ lv_v0, const float* __restrict__ lv_g0,
    const float* __restrict__ lv_b0,
    const float* __restrict__ lv_v1, const float* __restrict__ lv_g1,
    const float* __restrict__ lv_b1,
    const float* __restrict__ lv_v2, const float* __restrict__ lv_g2,
    u16* __restrict__ W1p, u16* __restrict__ W2p, u16* __restrict__ W0p,
    float* __restrict__ b1p, float* __restrict__ b0p) {
  int bid = blockIdx.x, tid = threadIdx.x;
  int l = tid & 63, w = tid >> 6;

  {  // W1p: one wave per padded row; wid = net*1200 + g*80 + u
    int wid = bid * 4 + w;                 // 0..2399
    int net = wid / 1200, rem = wid % 1200;
    int g = rem / 80, u = rem % 80;
    u16* o = W1p + (size_t)wid * 1024;
    if (u < sz_of(g)) {
      int j = p_of(lb_of(g) + u);
      const float* v = (net ? lv_v1 : mu_v1) + (size_t)j * Hh;
      float val[4][4]; float ss = 0.f;
      for (int ii = 0; ii < 4; ++ii)
        for (int t = 0; t < 4; ++t) {
          int kp = ii * 256 + 4 * l + t;
          float xx = v[p_of(kp)];
          val[ii][t] = xx; ss += xx * xx;
        }
      for (int s = 32; s; s >>= 1) ss += __shfl_xor(ss, s);
      float sc = ((net ? lv_g1 : mu_g1)[j]) * rsqrtf(ss);
      for (int ii = 0; ii < 4; ++ii) {
        int k0 = ii * 256 + 4 * l;
        u16x4 wv;
        for (int t = 0; t < 4; ++t)
          wv[t] = f2bf((g >= g_of(k0 + t)) ? sc * val[ii][t] : 0.f);
        *(u16x4*)(o + k0) = wv;
      }
    } else {
      u16x4 z = {0, 0, 0, 0};
      for (int ii = 0; ii < 4; ++ii) *(u16x4*)(o + ii * 256 + 4 * l) = z;
    }
  }

  if (bid < 8) {  // W2p: one wave per (net, out-row)
    int wid2 = bid * 4 + w;                // 0..31
    int nn = wid2 >> 4, oi = wid2 & 15;
    const float* v = (nn ? lv_v2 : mu_v2) + (size_t)oi * Hh;
    float ss = 0.f;
    for (int ii = 0; ii < 4; ++ii) {
      f32x4 vv = *(const f32x4*)(v + ii * 256 + 4 * l);
      ss += vv[0]*vv[0] + vv[1]*vv[1] + vv[2]*vv[2] + vv[3]*vv[3];
    }
    for (int s = 32; s; s >>= 1) ss += __shfl_xor(ss, s);
    float sc = ((nn ? lv_g2 : mu_g2)[oi]) * rsqrtf(ss);
    for (int e = l; e < 15 * 104; e += 64) {
      int g = e / 104, u = e % 104;
      float val = 0.f;
      if (u < sz_of(g) && oi > g) val = sc * v[p_of(lb_of(g) + u)];
      W2p[nn * W2P_NET + g * (16 * 104) + oi * 104 + u] = f2bf(val);
    }
  }

  if (bid >= 8 && bid < 18) {  // W0p + b0p + b1p: one thread per padded unit
    int idx = (bid - 8) * 256 + tid;       // 0..2559
    if (idx < 2400) {
      int nn = idx / 1200, rem = idx % 1200;
      int g = rem / 80, u = rem % 80;
      u16* orow = W0p + nn * W0P_NET + g * (80 * 32) + u * 32;
      if (u < sz_of(g)) {
        int j = p_of(lb_of(g) + u);
        const float* v = (nn ? lv_v0 : mu_v0) + j * Dd;
        float vv[16]; float ss = 0.f;
        for (int k = 0; k < 16; ++k) { vv[k] = v[k]; ss += vv[k] * vv[k]; }
        float sc = ((nn ? lv_g0 : mu_g0)[j]) * rsqrtf(ss);
        for (int k = 0; k < 16; ++k)
          orow[k] = f2bf((g >= k) ? sc * vv[k] : 0.f);
        for (int k = 16; k < 32; ++k) orow[k] = 0;
        b0p[nn * 1200 + g * 80 + u] = (nn ? lv_b0 : mu_b0)[j];
        b1p[nn * 1200 + g * 80 + u] = (nn ? lv_b1 : mu_b1)[j];
      } else {
        for (int k = 0; k < 32; ++k) orow[k] = 0;
        b0p[nn * 1200 + g * 80 + u] = 0.f;
        b1p[nn * 1200 + g * 80 + u] = 0.f;
      }
    }
  }
}

// --------------------------- W1 fragment transform -------------------------
// One wave per (net, g, kt) tile: read linear W1p (u16x8, 16-row segments),
// write MFMA-fragment-ordered W1f (fully coalesced per frag).
__global__ __launch_bounds__(256) void prep_w1f(
    const u16* __restrict__ W1p, u16* __restrict__ W1f) {
  int t = blockIdx.x * 4 + (threadIdx.x >> 6);   // 0..479
  int l = threadIdx.x & 63;
  int net = t / 240, rem = t % 240;
  int g = rem >> 4, kt = rem & 15;
  if (kt >= ((lb_of(g + 1) + 63) >> 6)) return;  // unused kt slice
  const u16* src = W1p + (size_t)(net * 1200 + g * 80) * 1024;
  u16* dst = W1f + ((size_t)((net * 15 + g) * 16 + kt) * 10) * 512;
  for (int nf = 0; nf < 5; ++nf)
    for (int kk = 0; kk < 2; ++kk) {
      int u = nf * 16 + (l & 15);
      int k = kt * 64 + kk * 32 + ((l >> 4) << 3);
      u16x8 v = *(const u16x8*)(src + (size_t)u * 1024 + k);
      *(u16x8*)(dst + (size_t)(nf * 2 + kk) * 512 + l * 8) = v;
    }
}

// --------------------------- main (one dispatch, 128 blocks) ---------------
// Block owns 16 rows; 8 waves = (net, kq 4-way K-split). h0 in LDS.
__global__ __launch_bounds__(512) void afmade_main(
    const u16* __restrict__ W1f, const u16* __restrict__ W2p,
    const u16* __restrict__ W0p,
    const float* __restrict__ b1p, const float* __restrict__ b0p,
    const float* __restrict__ b2_mu, const float* __restrict__ b2_lv,
    const float* __restrict__ x, float* __restrict__ out) {
  __shared__ u16 h0L[2][16][1040];        // 66,560 B (stride 2080B: ~4-way)
  __shared__ float sPart[2][4][16][80];   // 40,960 B
  __shared__ u16 sH1[2][16][104];         // 6,656 B (units 80..95 stay zero)
  __shared__ u16 yb[16][40];              // cols 16..31 stay zero
  __shared__ float sX[16][16];
  __shared__ float sB1L[2400];
  __shared__ float sB0L[2400];
  __shared__ float sB2[2][16];
  __shared__ float sLsum[16];

  const int tid = threadIdx.x;
  const int l = tid & 63, w = tid >> 6;
  const int net = w >> 2, kq = w & 3;
  const int lr = l & 15, lk = l >> 4;
  const int b0g = blockIdx.x * 16;

  {  // zero-init LDS state (zeros make masked-weight products exact)
    u16x8 z = {0, 0, 0, 0, 0, 0, 0, 0};
    for (int e = tid; e < 4160; e += 512) ((u16x8*)h0L)[e] = z;
    for (int e = tid; e < 416; e += 512) ((u16x8*)sH1)[e] = z;
    for (int e = tid; e < 80; e += 512) ((u16x8*)yb)[e] = z;
  }
  for (int e = tid; e < 256; e += 512)
    sX[e >> 4][e & 15] = x[(size_t)(b0g + (e >> 4)) * 16 + (e & 15)];
  for (int e = tid; e < 2400; e += 512) { sB1L[e] = b1p[e]; sB0L[e] = b0p[e]; }
  if (tid < 16) sB2[0][tid] = b2_mu[tid];
  else if (tid < 32) sB2[1][tid - 16] = b2_lv[tid - 16];
  else if (tid < 48) sLsum[tid - 32] = 0.f;
  f32x4 mlacc0 = {0.f, 0.f, 0.f, 0.f};   // live in wave 0 (mu net)
  f32x4 mlacc1 = {0.f, 0.f, 0.f, 0.f};   // live in wave 0 (lv net)
  __syncthreads();

  for (int s = 0; s < 16; ++s) {
    if (s > 0) {
      const int g = s - 1;
      const int ktn = (lb_of(s) + 63) >> 6;
      // wave 0: issue both nets' W2 frag loads early (drain at bar1)
      s16x8 w2f[6];
      if (w == 0) {
#pragma unroll
        for (int c = 0; c < 3; ++c) {
          w2f[c] = *(const s16x8*)(W2p + g * (16 * 104) + lr * 104 +
                                   c * 32 + lk * 8);
          w2f[3 + c] = *(const s16x8*)(W2p + W2P_NET + g * (16 * 104) +
                                       lr * 104 + c * 32 + lk * 8);
        }
      }
      // GEMM: h1 group g partials, K split 4 ways over kq
      f32x4 hacc[5] = {};
      for (int kt = kq; kt < ktn; kt += 4) {
        const u16* fp = W1f +
            ((size_t)((net * 15 + g) * 16 + kt) * 10) * 512 + l * 8;
        s16x8 bf[5][2];
#pragma unroll
        for (int nf = 0; nf < 5; ++nf)
#pragma unroll
          for (int kk = 0; kk < 2; ++kk)
            bf[nf][kk] = *(const s16x8*)(fp + (nf * 2 + kk) * 512);
        s16x8 a0 = *(const s16x8*)(&h0L[net][lr][kt * 64 + lk * 8]);
        s16x8 a1 = *(const s16x8*)(&h0L[net][lr][kt * 64 + 32 + lk * 8]);
#pragma unroll
        for (int nf = 0; nf < 5; ++nf) {
          hacc[nf] = __builtin_amdgcn_mfma_f32_16x16x32_bf16(
              a0, bf[nf][0], hacc[nf], 0, 0, 0);
          hacc[nf] = __builtin_amdgcn_mfma_f32_16x16x32_bf16(
              a1, bf[nf][1], hacc[nf], 0, 0, 0);
        }
      }
#pragma unroll
      for (int nf = 0; nf < 5; ++nf)
#pragma unroll
        for (int reg = 0; reg < 4; ++reg)
          sPart[net][kq][lk * 4 + reg][nf * 16 + lr] = hacc[nf][reg];
      __syncthreads();                       // bar1
      // reduce 4 partials + bias + elu -> sH1 (2560 outputs, 5/thread)
      for (int c = 0; c < 5; ++c) {
        int idx = c * 512 + tid;
        int nn = idx / 1280;
        int rem = idx - nn * 1280;
        int rr = rem / 80, uu = rem - rr * 80;
        float v = sPart[nn][0][rr][uu] + sPart[nn][1][rr][uu] +
                  sPart[nn][2][rr][uu] + sPart[nn][3][rr][uu] +
                  sB1L[nn * 1200 + g * 80 + uu];
        sH1[nn][rr][uu] = f2bf(elu(v));
      }
      __syncthreads();                       // bar2
      // ML += h1grp @ W2g^T for BOTH nets, in wave 0 (K=96; pads zero)
      if (w == 0) {
#pragma unroll
        for (int c = 0; c < 3; ++c) {
          s16x8 a0 = *(const s16x8*)(&sH1[0][lr][c * 32 + lk * 8]);
          mlacc0 = __builtin_amdgcn_mfma_f32_16x16x32_bf16(
              a0, w2f[c], mlacc0, 0, 0, 0);
          s16x8 a1v = *(const s16x8*)(&sH1[1][lr][c * 32 + lk * 8]);
          mlacc1 = __builtin_amdgcn_mfma_f32_16x16x32_bf16(
              a1v, w2f[3 + c], mlacc1, 0, 0, 0);
        }
      }
    }
    // y update (wave 0, lanes lr==s hold ML column s; 4 lanes x 4 rows)
    if (w == 0 && lr == s) {
#pragma unroll
      for (int reg = 0; reg < 4; ++reg) {
        int r = lk * 4 + reg;
        float mu = mlacc0[reg] + sB2[0][s];
        float lv = mlacc1[reg] + sB2[1][s];
        float ls = 0.5f * lv;
        float yv = (sX[r][s] - mu) / (__expf(ls) + EPSV);
        out[(size_t)(b0g + r) * 16 + s] = yv;
        yb[r][s] = f2bf(yv);
        float ns = sLsum[r] + ls;
        sLsum[r] = ns;
        if (s == 15) out[Bb * 16 + b0g + r] = ns;
      }
    }
    __syncthreads();                         // bar3 (yb visible)
    if (s < 15) {
      // h0 group s = elu(y @ W0g^T + b0) -> h0L
      const int LbS = lb_of(s), szS = sz_of(s);
      const u16* W0g = W0p + net * W0P_NET + s * (80 * 32);
      s16x8 yfrag = *(const s16x8*)(&yb[lr][lk * 8]);
#pragma unroll
      for (int t2 = 0; t2 < 2; ++t2) {
        int nf = kq + t2 * 4;
        if (nf < 5) {
          int unit = nf * 16 + lr;
          s16x8 wf = *(const s16x8*)(W0g + unit * 32 + lk * 8);
          f32x4 h = __builtin_amdgcn_mfma_f32_16x16x32_bf16(
              yfrag, wf, (f32x4){0.f, 0.f, 0.f, 0.f}, 0, 0, 0);
          if (unit < szS) {
            float bias = sB0L[net * 1200 + s * 80 + unit];
#pragma unroll
            for (int reg = 0; reg < 4; ++reg)
              h0L[net][lk * 4 + reg][LbS + unit] = f2bf(elu(h[reg] + bias));
          }
        }
      }
      __syncthreads();                       // bar4 (h0L stable)
    }
  }
}

// --------------------------- launch ----------------------------------------

extern "C" void kernel_launch(void* const* d_in, const int* in_sizes, int n_in,
                              void* d_out, int out_size, void* d_ws, size_t ws_size,
                              hipStream_t stream) {
  const float* x     = (const float*)d_in[0];
  const float* mu_v0 = (const float*)d_in[1];
  const float* mu_g0 = (const float*)d_in[2];
  const float* mu_b0 = (const float*)d_in[3];
  const float* mu_v1 = (const float*)d_in[4];
  const float* mu_g1 = (const float*)d_in[5];
  const float* mu_b1 = (const float*)d_in[6];
  const float* mu_v2 = (const float*)d_in[7];
  const float* mu_g2 = (const float*)d_in[8];
  const float* mu_b2 = (const float*)d_in[9];
  const float* lv_v0 = (const float*)d_in[10];
  const float* lv_g0 = (const float*)d_in[11];
  const float* lv_b0 = (const float*)d_in[12];
  const float* lv_v1 = (const float*)d_in[13];
  const float* lv_g1 = (const float*)d_in[14];
  const float* lv_b1 = (const float*)d_in[15];
  const float* lv_v2 = (const float*)d_in[16];
  const float* lv_g2 = (const float*)d_in[17];
  const float* lv_b2 = (const float*)d_in[18];

  char* ws = (char*)d_ws;
  u16*   W1p = (u16*)(ws);                       // 4,915,200 B
  u16*   W2p = (u16*)(ws + 4915200);             //    99,840 B
  u16*   W0p = (u16*)(ws + 5015040);             //   153,600 B
  float* b1p = (float*)(ws + 5168640);           //     9,600 B
  float* b0p = (float*)(ws + 5178240);           //     9,600 B
  u16*   W1f = (u16*)(ws + 5187840);             // 4,915,200 B

  prep_all<<<600, 256, 0, stream>>>(
      mu_v0, mu_g0, mu_b0, mu_v1, mu_g1, mu_b1, mu_v2, mu_g2,
      lv_v0, lv_g0, lv_b0, lv_v1, lv_g1, lv_b1, lv_v2, lv_g2,
      W1p, W2p, W0p, b1p, b0p);
  prep_w1f<<<120, 256, 0, stream>>>(W1p, W1f);

  afmade_main<<<128, 512, 0, stream>>>(W1f, W2p, W0p, b1p, b0p,
                                       mu_b2, lv_b2, x, (float*)d_out);
}